// Round 8
// baseline (469.508 us; speedup 1.0000x reference)
//
#include <hip/hip_runtime.h>
#include <hip/hip_bf16.h>

#define BB 128
#define TT 512
#define EE 128
#define HH 256
#define MM 1024
#define CC 5

typedef _Float16 h2 __attribute__((ext_vector_type(2)));
typedef __fp16 f16x2 __attribute__((ext_vector_type(2)));
typedef __fp16 f16x8 __attribute__((ext_vector_type(8)));
typedef float  f32x4 __attribute__((ext_vector_type(4)));

__device__ inline h2 mkh2(float a, float b) {
    return __builtin_bit_cast(h2, __builtin_amdgcn_cvt_pkrtz(a, b));
}

// pack 8 f32 -> 8 f16 (one MFMA operand fragment)
__device__ inline f16x8 pack8(float4 lo, float4 hi) {
    union { f16x2 h[4]; f16x8 v; } u;
    u.h[0] = __builtin_amdgcn_cvt_pkrtz(lo.x, lo.y);
    u.h[1] = __builtin_amdgcn_cvt_pkrtz(lo.z, lo.w);
    u.h[2] = __builtin_amdgcn_cvt_pkrtz(hi.x, hi.y);
    u.h[3] = __builtin_amdgcn_cvt_pkrtz(hi.z, hi.w);
    return u.v;
}

__device__ inline float dot2f(h2 a, h2 b, float c) {
#if __has_builtin(__builtin_amdgcn_fdot2)
    return __builtin_amdgcn_fdot2(a, b, c, false);
#else
    return c + (float)a.x * (float)b.x + (float)a.y * (float)b.y;
#endif
}

// Quad butterfly sum via DPP: xor1 (0xB1) + xor2 (0x4E), VALU pipe.
__device__ inline float dpp_add4(float x) {
    int t = __builtin_amdgcn_update_dpp(0, __builtin_bit_cast(int, x), 0xB1, 0xF, 0xF, true);
    x += __builtin_bit_cast(float, t);
    t = __builtin_amdgcn_update_dpp(0, __builtin_bit_cast(int, x), 0x4E, 0xF, 0xF, true);
    x += __builtin_bit_cast(float, t);
    return x;
}

// 8-lane butterfly: xor4 via shfl, then the quad butterfly.
__device__ inline float add8(float x) {
    x += __shfl_xor(x, 4, 64);
    return dpp_add4(x);
}

__device__ inline float fast_tanh(float x) {
    float e = __expf(2.0f * x);
    return 1.0f - 2.0f / (e + 1.0f);
}

// ---------------------------------------------------------------------------
// K1 (MFMA GEMM): u[tok][ch] = bias[ch] + emb[x[tok]] @ W_ih^T, f16 out.
// (unchanged from R7 — it left the top-5)
// ---------------------------------------------------------------------------
__global__ __launch_bounds__(256, 2)
void k_embed(const int* __restrict__ x,
             const float* __restrict__ emb, const float* __restrict__ W_ih,
             const float* __restrict__ b_ih, const float* __restrict__ b_hh,
             _Float16* __restrict__ u)
{
    const int tb   = blockIdx.x;
    const int tid  = threadIdx.x;
    const int wv   = tid >> 6;
    const int lane = tid & 63;
    const int l15  = lane & 15;
    const int quad = lane >> 4;

    __shared__ __align__(16) char lds[32 * 512];

    f16x8 bf[4][4];
    float bias[4];
    #pragma unroll
    for (int ct = 0; ct < 4; ++ct) {
        const int n = 64 * wv + 16 * ct + l15;
        const float* wp = W_ih + (size_t)n * EE;
        #pragma unroll
        for (int kc = 0; kc < 4; ++kc) {
            const float4* p = (const float4*)(wp + 32 * kc + 8 * quad);
            bf[ct][kc] = pack8(p[0], p[1]);
        }
        bias[ct] = b_ih[n] + b_hh[n];
    }

    {
        const int r = tid >> 3;
        const int s = tid & 7;
        const int tok = x[tb * 32 + r];
        const float4* ep = (const float4*)(emb + (size_t)tok * EE + 16 * s);
        float4 a = ep[0], b = ep[1], c = ep[2], d = ep[3];
        *(f16x8*)(lds + r * 256 + 32 * s)      = pack8(a, b);
        *(f16x8*)(lds + r * 256 + 32 * s + 16) = pack8(c, d);
    }
    __syncthreads();

    f32x4 acc[2][4];
    #pragma unroll
    for (int rt = 0; rt < 2; ++rt)
        #pragma unroll
        for (int ct = 0; ct < 4; ++ct)
            acc[rt][ct] = (f32x4){bias[ct], bias[ct], bias[ct], bias[ct]};

    #pragma unroll
    for (int kc = 0; kc < 4; ++kc) {
        const int ko = (32 * kc + 8 * quad) * 2;
        f16x8 a0 = *(const f16x8*)(lds + (l15)      * 256 + ko);
        f16x8 a1 = *(const f16x8*)(lds + (16 + l15) * 256 + ko);
        #pragma unroll
        for (int ct = 0; ct < 4; ++ct) {
            acc[0][ct] = __builtin_amdgcn_mfma_f32_16x16x32_f16(a0, bf[ct][kc], acc[0][ct], 0, 0, 0);
            acc[1][ct] = __builtin_amdgcn_mfma_f32_16x16x32_f16(a1, bf[ct][kc], acc[1][ct], 0, 0, 0);
        }
    }
    __syncthreads();

    #pragma unroll
    for (int rt = 0; rt < 2; ++rt) {
        #pragma unroll
        for (int ct = 0; ct < 4; ++ct) {
            const int chb = (64 * wv + 16 * ct + l15) * 2;
            #pragma unroll
            for (int rg = 0; rg < 4; ++rg) {
                const int tok = 16 * rt + 4 * quad + rg;
                *(_Float16*)(lds + tok * 512 + chb) = (_Float16)acc[rt][ct][rg];
            }
        }
    }
    __syncthreads();

    {
        char* dst = (char*)u + (size_t)tb * 16384 + tid * 64;
        const char* src = lds + tid * 64;
        #pragma unroll
        for (int q = 0; q < 4; ++q)
            *(float4*)(dst + 16 * q) = *(const float4*)(src + 16 * q);
    }
}

// ---------------------------------------------------------------------------
// K2: serial scan, one WG per batch element — now 512 threads (8 waves =
// 2 waves/SIMD) so co-resident waves hide each other's lgkm/barrier stalls,
// which R1-R6's 4-wave lockstep could not. Split-K(8): thread (kc=tid&7,
// g=tid>>3) computes channels 4g..4g+3 over h-chunk [32kc,32kc+32) — 64
// dot2/thread (half of R6), 4 ds_read_b128/thread (32/CU, LDS-pipe neutral).
// Reduction: shfl_xor(4) + DPP quad butterfly; lane kc<4 keeps ch 4g+kc.
// Reads quad-permuted per kc: addr = kc*64 + ((i + (kc>>1))&3)*16 -> the 8
// distinct 16B addresses cover all 32 banks exactly once (conflict-free).
// u staged per 64 steps in LDS (inner loop LDS-only; no vmcnt drain).
// ---------------------------------------------------------------------------
__global__ __launch_bounds__(512, 1)
void k_rnn(const int* __restrict__ lengths, const float* __restrict__ W_hh,
           const _Float16* __restrict__ u, float* __restrict__ hn)
{
    const int b = blockIdx.x;
    const int tid = threadIdx.x;        // 0..511
    const int kc  = tid & 7;            // h-chunk [32kc, 32kc+32)
    const int g   = tid >> 3;           // 0..63, channels 4g..4g+3
    const int len = lengths[b];
    const int perm = kc >> 1;

    // W_hh rows 4g..4g+3, chunk cols, stored in the permuted iter order:
    // w[m][4i+z] pairs with hbuf bytes roff[i]+4z.  64 VGPRs.
    h2 w[4][16];
    #pragma unroll
    for (int m = 0; m < 4; ++m) {
        const float* wrow = W_hh + (size_t)(4 * g + m) * HH + 32 * kc;
        #pragma unroll
        for (int i = 0; i < 4; ++i) {
            const int piece = (i + perm) & 3;        // 8 h-values
            const float4* p = (const float4*)(wrow + piece * 8);
            float4 va = p[0], vb = p[1];
            w[m][4*i+0] = mkh2(va.x, va.y);
            w[m][4*i+1] = mkh2(va.z, va.w);
            w[m][4*i+2] = mkh2(vb.x, vb.y);
            w[m][4*i+3] = mkh2(vb.z, vb.w);
        }
    }

    __shared__ __align__(16) _Float16 hbuf[2][HH];    // 2 x 512B
    __shared__ __align__(16) char ubuf[64 * 512];     // 64 steps x 512B
    if (tid < 128) { ((float*)hbuf)[tid] = 0.f; ((float*)hbuf)[tid + 128] = 0.f; }

    int roff[4];
    #pragma unroll
    for (int i = 0; i < 4; ++i)
        roff[i] = kc * 64 + (((i + perm) & 3) << 4);

    const int ch = 4 * g + (kc & 3);    // this thread's kept channel (kc<4)

    __syncthreads();

    float hlast = 0.f;
    if (len > 0) {
        const char* ubase = (const char*)(u + ((size_t)b * TT + (TT - len)) * HH);
        const int totbytes = len * 512;
        int p = 0;
        for (int c = 0; c * 64 < len; ++c) {
            // ---- stage chunk c: 64 steps x 512B = 32KB, coalesced ----
            const int cbase = c * 32768;
            float4 stash[4];
            #pragma unroll
            for (int q = 0; q < 4; ++q) {
                int off = cbase + q * 8192 + tid * 16;
                off = (off > totbytes - 16) ? (totbytes - 16) : off;
                stash[q] = *(const float4*)(ubase + off);
            }
            #pragma unroll
            for (int q = 0; q < 4; ++q)
                *(float4*)(ubuf + q * 8192 + tid * 16) = stash[q];
            __syncthreads();
            // ---- 64 LDS-only steps ----
            const int steps = (len - c * 64 < 64) ? (len - c * 64) : 64;
            for (int s = 0; s < steps; ++s) {
                const char* hb = (const char*)hbuf[p];
                const _Float16 uv = *(const _Float16*)(ubuf + s * 512 + ch * 2);
                float a0 = 0.f, a1 = 0.f, a2 = 0.f, a3 = 0.f;
                #pragma unroll
                for (int i = 0; i < 4; ++i) {
                    float4 hv = *(const float4*)(hb + roff[i]);  // conflict-free
                    h2* hp = (h2*)&hv;
                    #pragma unroll
                    for (int z = 0; z < 4; ++z) {
                        a0 = dot2f(w[0][4*i+z], hp[z], a0);
                        a1 = dot2f(w[1][4*i+z], hp[z], a1);
                        a2 = dot2f(w[2][4*i+z], hp[z], a2);
                        a3 = dot2f(w[3][4*i+z], hp[z], a3);
                    }
                }
                a0 = add8(a0); a1 = add8(a1); a2 = add8(a2); a3 = add8(a3);
                float v = (kc == 0 || kc == 4) ? a0
                        : (kc == 1 || kc == 5) ? a1
                        : (kc == 2 || kc == 6) ? a2 : a3;
                const float hnew = fast_tanh(v + (float)uv);
                hlast = hnew;
                if (kc < 4)                       // lanes kc>=4 are duplicates
                    hbuf[p ^ 1][ch] = (_Float16)hnew;
                __syncthreads();
                p ^= 1;
            }
        }
    }
    if (kc < 4) hn[(size_t)b * HH + ch] = hlast;  // len==0 -> 0, matches ref
}

// ---------------------------------------------------------------------------
// K3: MLP head + log_softmax. One block per batch row. (unchanged)
// ---------------------------------------------------------------------------
__global__ __launch_bounds__(256, 2)
void k_head(const float* __restrict__ hn, const float* __restrict__ W0,
            const float* __restrict__ b0, const float* __restrict__ W1,
            const float* __restrict__ b1, float* __restrict__ out)
{
    const int b = blockIdx.x;
    const int tid = threadIdx.x;
    __shared__ float sh[HH];
    __shared__ float sh1[MM];
    __shared__ float sred[CC][4];
    __shared__ float slog[CC];

    sh[tid] = hn[(size_t)b * HH + tid];
    __syncthreads();

    float acc[4];
    #pragma unroll
    for (int i = 0; i < 4; ++i) acc[i] = b0[tid + 256 * i];
    const float4* sh4 = (const float4*)sh;
    for (int k4 = 0; k4 < HH / 4; ++k4) {
        float4 hv = sh4[k4];
        #pragma unroll
        for (int i = 0; i < 4; ++i) {
            float4 wv = ((const float4*)(W0 + (size_t)(tid + 256 * i) * HH))[k4];
            acc[i] += wv.x * hv.x + wv.y * hv.y + wv.z * hv.z + wv.w * hv.w;
        }
    }
    #pragma unroll
    for (int i = 0; i < 4; ++i) sh1[tid + 256 * i] = fmaxf(acc[i], 0.f);
    __syncthreads();

    float pc[CC] = {0.f, 0.f, 0.f, 0.f, 0.f};
    for (int k = tid; k < MM; k += 256) {
        float hv = sh1[k];
        #pragma unroll
        for (int c = 0; c < CC; ++c) pc[c] += W1[(size_t)c * MM + k] * hv;
    }
    const int lane = tid & 63, wid = tid >> 6;
    #pragma unroll
    for (int c = 0; c < CC; ++c) {
        float v = pc[c];
        #pragma unroll
        for (int off = 32; off > 0; off >>= 1) v += __shfl_down(v, off, 64);
        if (lane == 0) sred[c][wid] = v;
    }
    __syncthreads();
    if (tid < CC) {
        float s = sred[tid][0] + sred[tid][1] + sred[tid][2] + sred[tid][3]
                + b1[tid];
        slog[tid] = fmaxf(s, 0.f);
    }
    __syncthreads();
    if (tid < CC) {
        float mx = slog[0];
        #pragma unroll
        for (int c = 1; c < CC; ++c) mx = fmaxf(mx, slog[c]);
        float se = 0.f;
        #pragma unroll
        for (int c = 0; c < CC; ++c) se += __expf(slog[c] - mx);
        out[(size_t)b * CC + tid] = slog[tid] - mx - __logf(se);
    }
}

// ---------------------------------------------------------------------------
extern "C" void kernel_launch(void* const* d_in, const int* in_sizes, int n_in,
                              void* d_out, int out_size, void* d_ws, size_t ws_size,
                              hipStream_t stream) {
    const int*   x       = (const int*)d_in[0];
    const int*   lengths = (const int*)d_in[1];
    const float* emb     = (const float*)d_in[2];
    const float* W_ih    = (const float*)d_in[3];
    const float* W_hh    = (const float*)d_in[4];
    const float* b_ih    = (const float*)d_in[5];
    const float* b_hh    = (const float*)d_in[6];
    const float* W0      = (const float*)d_in[7];
    const float* b0      = (const float*)d_in[8];
    const float* W1      = (const float*)d_in[9];
    const float* b1      = (const float*)d_in[10];
    float* out = (float*)d_out;

    _Float16* u  = (_Float16*)d_ws;
    float*    hn = (float*)((char*)d_ws + (size_t)BB * TT * HH * sizeof(_Float16));

    k_embed<<<(BB * TT) / 32, 256, 0, stream>>>(x, emb, W_ih, b_ih, b_hh, u);
    k_rnn  <<<BB, 512, 0, stream>>>(lengths, W_hh, u, hn);
    k_head <<<BB, 256, 0, stream>>>(hn, W0, b0, W1, b1, out);
}